// Round 4
// baseline (553.665 us; speedup 1.0000x reference)
//
#include <hip/hip_runtime.h>
#include <stdint.h>

#define VOCAB     128000
#define BINS      4096
#define BPR       16                // blocks per row in the stage pass
#define TPB1      512               // threads per block (stage pass)
#define CHUNK     (VOCAB / BPR)     // 8000 floats per block
#define N4C       (CHUNK / 4)       // 2000 float4 per block
#define CAND_CAP  3072              // per-row candidate capacity
#define FILT_CAP  512               // post-prune capacity in finalize
#define KEEP_CAP  128

__device__ __forceinline__ uint32_t rotl32(uint32_t x, uint32_t r) {
    return (x << r) | (x >> (32u - r));
}

// monotone float -> uint transform (total order)
__device__ __forceinline__ uint32_t f2ord(float f) {
    uint32_t u = __float_as_uint(f);
    return (u & 0x80000000u) ? ~u : (u | 0x80000000u);
}

// Threefry-2x32, 20 rounds, key = (0, 42)  [jax.random.key(42)] — verified round 1
__device__ __forceinline__ void threefry_0_42(uint32_t x0, uint32_t x1,
                                              uint32_t& o0, uint32_t& o1) {
    const uint32_t k0 = 0u, k1 = 42u;
    const uint32_t k2 = 0x1BD11BDAu ^ k0 ^ k1;
#define TF_RND(R) { x0 += x1; x1 = rotl32(x1, (R)); x1 ^= x0; }
    x0 += k0; x1 += k1;
    TF_RND(13) TF_RND(15) TF_RND(26) TF_RND(6)
    x0 += k1; x1 += k2 + 1u;
    TF_RND(17) TF_RND(29) TF_RND(16) TF_RND(24)
    x0 += k2; x1 += k0 + 2u;
    TF_RND(13) TF_RND(15) TF_RND(26) TF_RND(6)
    x0 += k0; x1 += k1 + 3u;
    TF_RND(17) TF_RND(29) TF_RND(16) TF_RND(24)
    x0 += k1; x1 += k2 + 4u;
    TF_RND(13) TF_RND(15) TF_RND(26) TF_RND(6)
    x0 += k2; x1 += k0 + 5u;
#undef TF_RND
    o0 = x0; o1 = x1;
}

__device__ __forceinline__ float gumbel_at(uint64_t flat) {
    uint32_t o0, o1;
    threefry_0_42((uint32_t)(flat >> 32), (uint32_t)flat, o0, o1);
    uint32_t bits = o0 ^ o1;
    float f = __uint_as_float((bits >> 9) | 0x3F800000u) - 1.0f;
    float u = (f == 0.0f) ? 1.17549435e-38f : f;
    return -logf(-logf(u));
}

// ---------------------------------------------------------------------------
// K1: per-(row,chunk) block. Pass A: read chunk ONCE from HBM, scale, store
// scores to LDS, LDS histogram. Pass B: local top-K bin threshold. Pass C:
// re-read from LDS (no HBM/L3 round trip), push candidates to global ws.
// Pass D: zero-fill the probs chunk. HBM traffic = 64 MB R + 64 MB W exactly.
// ---------------------------------------------------------------------------
extern "C" __global__ __launch_bounds__(TPB1)
void stage_kernel(const float* __restrict__ logits,
                  const float* __restrict__ temp_p,
                  const int*   __restrict__ topk_p,
                  float* __restrict__ out,
                  float* __restrict__ candV,
                  int*   __restrict__ candI,
                  int*   __restrict__ counters,
                  int batch, int cap) {
    const int row = blockIdx.x / BPR;
    const int sub = blockIdx.x % BPR;
    const int c0  = sub * CHUNK;
    const int tid = threadIdx.x;

    __shared__ float4   sChunk[N4C];     // 32 KB scaled scores
    __shared__ uint32_t hist[BINS];      // 16 KB
    __shared__ int      s_grp[256];
    __shared__ int      s_tbin;

    for (int i = tid; i < BINS; i += TPB1) hist[i] = 0u;
    __syncthreads();

    const float rT = 1.0f / temp_p[0];   // x*(1/T): <=1ulp vs x/T; gaps >> ulp
    const int   K  = topk_p[0];

    const float4* rowp = (const float4*)(logits + (size_t)row * VOCAB) + (c0 >> 2);
    float4*       orow = (float4*)(out + batch + (size_t)row * VOCAB) + (c0 >> 2);

    // pass A: single HBM read -> LDS stage + histogram
    #pragma unroll 2
    for (int i = tid; i < N4C; i += TPB1) {
        float4 v = rowp[i];
        float4 s;
        s.x = v.x * rT; s.y = v.y * rT; s.z = v.z * rT; s.w = v.w * rT;
        sChunk[i] = s;
        atomicAdd(&hist[f2ord(s.x) >> 20], 1u);
        atomicAdd(&hist[f2ord(s.y) >> 20], 1u);
        atomicAdd(&hist[f2ord(s.z) >> 20], 1u);
        atomicAdd(&hist[f2ord(s.w) >> 20], 1u);
    }
    __syncthreads();

    // pass B: local top-K bin threshold (group sums + serial top-down scan)
    if (tid < 256) {
        int s = 0;
        #pragma unroll
        for (int b = 0; b < 16; ++b) s += (int)hist[tid * 16 + b];
        s_grp[tid] = s;
    }
    __syncthreads();
    if (tid == 0) {
        int cum = 0, g = 255;
        for (; g > 0; --g) {
            if (cum + s_grp[g] >= K) break;
            cum += s_grp[g];
        }
        int tb = g * 16;
        for (int b = g * 16 + 15; ; --b) {
            cum += (int)hist[b];
            if (cum >= K || b == g * 16) { tb = b; break; }
        }
        s_tbin = tb;
    }
    __syncthreads();
    const uint32_t tbin = (uint32_t)s_tbin;

    // pass C: re-read scores from LDS, push candidates >= threshold
    int* ctr = &counters[row];
    float* cVrow = candV + (size_t)row * cap;
    int*   cIrow = candI + (size_t)row * cap;
    for (int i = tid; i < N4C; i += TPB1) {
        float4 s = sChunk[i];
        float ss[4] = { s.x, s.y, s.z, s.w };
        int e = c0 + i * 4;
        #pragma unroll
        for (int c = 0; c < 4; ++c) {
            if ((f2ord(ss[c]) >> 20) >= tbin) {
                int p = atomicAdd(ctr, 1);
                if (p < cap) { cVrow[p] = ss[c]; cIrow[p] = e + c; }
            }
        }
    }

    // pass D: zero-fill probs chunk (independent write stream)
    const float4 z4 = make_float4(0.0f, 0.0f, 0.0f, 0.0f);
    for (int i = tid; i < N4C; i += TPB1) orow[i] = z4;
}

// ---------------------------------------------------------------------------
// K2: per-row finalize. Prune candidates via exact 4096-bin hist (kth bin),
// rank-sort the ~160 survivors, then the verified serial top-k/top-p math
// with PARALLEL expf, Gumbel-argmax, scatter probs + token.
// ---------------------------------------------------------------------------
extern "C" __global__ __launch_bounds__(512)
void finalize_kernel(const float* __restrict__ topp_p,
                     const int*   __restrict__ topk_p,
                     const float* __restrict__ candV,
                     const int*   __restrict__ candI,
                     const int*   __restrict__ counters,
                     float* __restrict__ out,
                     int batch, int cap) {
    const int row  = blockIdx.x;
    const int tid  = threadIdx.x;
    const int nthr = blockDim.x;

    const float thresh = 1.0f - topp_p[0];
    const int   K      = topk_p[0];

    __shared__ float    cV[CAND_CAP];
    __shared__ int      cI[CAND_CAP];
    __shared__ uint32_t h2[BINS];
    __shared__ int      s_grp[256];
    __shared__ float    fV[FILT_CAP];
    __shared__ int      fI[FILT_CAP];
    __shared__ float    sV[FILT_CAP];
    __shared__ int      sI[FILT_CAP];
    __shared__ float    eArr[KEEP_CAP * 2];
    __shared__ float    s_gs[KEEP_CAP];
    __shared__ int      s_bstar, s_cnt2, s_Kp, s_M, s_token;
    __shared__ float    s_Z2;

    const int n = min(counters[row], cap);
    const float* cVrow = candV + (size_t)row * cap;
    const int*   cIrow = candI + (size_t)row * cap;
    for (int i = tid; i < n; i += nthr) { cV[i] = cVrow[i]; cI[i] = cIrow[i]; }
    for (int i = tid; i < BINS; i += nthr) h2[i] = 0u;
    if (tid == 0) s_cnt2 = 0;
    __syncthreads();

    // exact kth-value bin among candidates (superset of global top-K)
    for (int i = tid; i < n; i += nthr) atomicAdd(&h2[f2ord(cV[i]) >> 20], 1u);
    __syncthreads();
    if (tid < 256) {
        int s = 0;
        #pragma unroll
        for (int b = 0; b < 16; ++b) s += (int)h2[tid * 16 + b];
        s_grp[tid] = s;
    }
    __syncthreads();
    if (tid == 0) {
        int cum = 0, g = 255;
        for (; g > 0; --g) {
            if (cum + s_grp[g] >= K) break;
            cum += s_grp[g];
        }
        int tb = g * 16;
        for (int b = g * 16 + 15; ; --b) {
            cum += (int)h2[b];
            if (cum >= K || b == g * 16) { tb = b; break; }
        }
        s_bstar = tb;
    }
    __syncthreads();
    const uint32_t bstar = (uint32_t)s_bstar;

    // filter to bin >= bstar (keeps all >= kth value, incl. ties)
    for (int i = tid; i < n; i += nthr) {
        if ((f2ord(cV[i]) >> 20) >= bstar) {
            int p = atomicAdd(&s_cnt2, 1);
            if (p < FILT_CAP) { fV[p] = cV[i]; fI[p] = cI[i]; }
        }
    }
    __syncthreads();
    const int n2 = min(s_cnt2, FILT_CAP);

    // rank sort descending (unique total order via index tiebreak)
    for (int j = tid; j < n2; j += nthr) {
        float vj = fV[j]; int ij = fI[j];
        int r = 0;
        for (int l = 0; l < n2; ++l) {
            float vl = fV[l];
            r += (vl > vj) || (vl == vj && fI[l] < ij);
        }
        sV[r] = vj; sI[r] = ij;
    }
    __syncthreads();

    // Kp = top-k survivor count (ties at kth kept), then parallel expf
    if (tid == 0) {
        int Keff = min(K, n2);
        float kth = sV[Keff - 1];
        int Kp = Keff;
        while (Kp < n2 && sV[Kp] == kth) ++Kp;
        if (Kp > KEEP_CAP * 2) Kp = KEEP_CAP * 2;
        s_Kp = Kp;
    }
    __syncthreads();
    const int Kp = s_Kp;
    const float m = sV[0];
    for (int j = tid; j < Kp; j += nthr) eArr[j] = expf(sV[j] - m);
    __syncthreads();

    // serial part is adds/divides only (verified accumulation order)
    if (tid == 0) {
        float Z = 0.0f;
        for (int j = Kp - 1; j >= 0; --j) Z += eArr[j];
        float cum = 0.0f; int jcut = 0;
        for (int j = Kp - 1; j >= 0; --j) {
            cum += eArr[j] / Z;
            if (cum > thresh) { jcut = j; break; }
        }
        int M = jcut + 1;
        if (M > KEEP_CAP) M = KEEP_CAP;
        float Z2 = 0.0f;
        for (int j = 0; j < M; ++j) Z2 += eArr[j];
        s_M = M; s_Z2 = Z2;
    }
    __syncthreads();
    const int M = s_M;
    const float Z2 = s_Z2;

    if (tid < M) {
        uint64_t flat = (uint64_t)row * VOCAB + (uint32_t)sI[tid];
        s_gs[tid] = sV[tid] + gumbel_at(flat);
    }
    __syncthreads();
    if (tid == 0) {
        float bs = -__builtin_inff(); int bi = 0x7fffffff;
        for (int j = 0; j < M; ++j) {
            float s = s_gs[j]; int c = sI[j];
            if (s > bs || (s == bs && c < bi)) { bs = s; bi = c; }
        }
        s_token = bi;
    }
    __syncthreads();

    // probs row already zeroed by K1 — scatter kept probs + token
    for (int j = tid; j < M; j += nthr) {
        out[batch + (size_t)row * VOCAB + sI[j]] = eArr[j] / Z2;
    }
    if (tid == 0) out[row] = (float)s_token;
}

extern "C" void kernel_launch(void* const* d_in, const int* in_sizes, int n_in,
                              void* d_out, int out_size, void* d_ws, size_t ws_size,
                              hipStream_t stream) {
    (void)n_in; (void)out_size;
    const float* logits = (const float*)d_in[0];
    const float* temp   = (const float*)d_in[1];
    const float* topp   = (const float*)d_in[2];
    const int*   topk   = (const int*)d_in[3];
    float* out = (float*)d_out;

    const int batch = in_sizes[0] / VOCAB;

    // ws layout: [counters: batch ints][candV: batch*cap floats][candI: batch*cap ints]
    size_t ctr_bytes = ((size_t)batch * sizeof(int) + 255) & ~(size_t)255;
    int cap = CAND_CAP;
    if (ws_size > ctr_bytes) {
        size_t per_row = (ws_size - ctr_bytes) / ((size_t)batch * 8);
        if (per_row < (size_t)cap) cap = (int)per_row;
    }
    int*   counters = (int*)d_ws;
    float* candV    = (float*)((char*)d_ws + ctr_bytes);
    int*   candI    = (int*)(candV + (size_t)batch * cap);

    hipMemsetAsync(counters, 0, (size_t)batch * sizeof(int), stream);

    stage_kernel<<<batch * BPR, TPB1, 0, stream>>>(
        logits, temp, topk, out, candV, candI, counters, batch, cap);

    finalize_kernel<<<batch, 512, 0, stream>>>(
        topp, topk, candV, candI, counters, out, batch, cap);
}

// Round 5
// 108.651 us; speedup vs baseline: 5.0958x; 5.0958x over previous
//
#include <hip/hip_runtime.h>
#include <stdint.h>

#define VOCAB     128000
#define BINS      4096
#define BPR       2                 // blocks per row -> 256 blocks = 1 per CU
#define TPB1      1024              // threads per block (stage pass)
#define CHUNK     (VOCAB / BPR)     // 64000 floats per block
#define N4C       (CHUNK / 4)       // 16000 float4 per block
#define CAND_CAP  2048              // per-row candidate capacity
#define FILT_CAP  512               // post-prune capacity in finalize
#define KEEP_CAP  128

__device__ __forceinline__ uint32_t rotl32(uint32_t x, uint32_t r) {
    return (x << r) | (x >> (32u - r));
}

// monotone float -> uint transform (total order)
__device__ __forceinline__ uint32_t f2ord(float f) {
    uint32_t u = __float_as_uint(f);
    return (u & 0x80000000u) ? ~u : (u | 0x80000000u);
}

// Threefry-2x32, 20 rounds, key = (0, 42)  [jax.random.key(42)] — verified round 1
__device__ __forceinline__ void threefry_0_42(uint32_t x0, uint32_t x1,
                                              uint32_t& o0, uint32_t& o1) {
    const uint32_t k0 = 0u, k1 = 42u;
    const uint32_t k2 = 0x1BD11BDAu ^ k0 ^ k1;
#define TF_RND(R) { x0 += x1; x1 = rotl32(x1, (R)); x1 ^= x0; }
    x0 += k0; x1 += k1;
    TF_RND(13) TF_RND(15) TF_RND(26) TF_RND(6)
    x0 += k1; x1 += k2 + 1u;
    TF_RND(17) TF_RND(29) TF_RND(16) TF_RND(24)
    x0 += k2; x1 += k0 + 2u;
    TF_RND(13) TF_RND(15) TF_RND(26) TF_RND(6)
    x0 += k0; x1 += k1 + 3u;
    TF_RND(17) TF_RND(29) TF_RND(16) TF_RND(24)
    x0 += k1; x1 += k2 + 4u;
    TF_RND(13) TF_RND(15) TF_RND(26) TF_RND(6)
    x0 += k2; x1 += k0 + 5u;
#undef TF_RND
    o0 = x0; o1 = x1;
}

__device__ __forceinline__ float gumbel_at(uint64_t flat) {
    uint32_t o0, o1;
    threefry_0_42((uint32_t)(flat >> 32), (uint32_t)flat, o0, o1);
    uint32_t bits = o0 ^ o1;
    float f = __uint_as_float((bits >> 9) | 0x3F800000u) - 1.0f;
    float u = (f == 0.0f) ? 1.17549435e-38f : f;
    return -logf(-logf(u));
}

// ---------------------------------------------------------------------------
// K1: R1's structure verbatim, half-row per block (256 blocks = 1/CU).
// pass 1: read chunk, histogram scores = x/T.  pass B: local top-K bin.
// pass C: re-read chunk (L2/L3-hot), push candidates to per-row global list.
// pass D: zero-fill probs chunk.
// Union of per-half-row top-K supersets the global top-K.
// ---------------------------------------------------------------------------
extern "C" __global__ __launch_bounds__(TPB1)
void stage_kernel(const float* __restrict__ logits,
                  const float* __restrict__ temp_p,
                  const int*   __restrict__ topk_p,
                  float* __restrict__ out,
                  float* __restrict__ candV,
                  int*   __restrict__ candI,
                  int*   __restrict__ counters,
                  int batch, int cap) {
    const int row = blockIdx.x / BPR;
    const int sub = blockIdx.x % BPR;
    const int c0  = sub * CHUNK;
    const int tid = threadIdx.x;

    const float T = temp_p[0];
    const int   K = topk_p[0];

    __shared__ int hist[BINS];
    __shared__ int s_grp[256];
    __shared__ int s_tbin;

    for (int i = tid; i < BINS; i += TPB1) hist[i] = 0;
    __syncthreads();

    const float4* rowp = (const float4*)(logits + (size_t)row * VOCAB) + (c0 >> 2);
    float4*       orow = (float4*)(out + batch + (size_t)row * VOCAB) + (c0 >> 2);

    // pass 1: histogram only (R1 structure)
    for (int i = tid; i < N4C; i += TPB1) {
        float4 v = rowp[i];
        atomicAdd(&hist[f2ord(v.x / T) >> 20], 1);
        atomicAdd(&hist[f2ord(v.y / T) >> 20], 1);
        atomicAdd(&hist[f2ord(v.z / T) >> 20], 1);
        atomicAdd(&hist[f2ord(v.w / T) >> 20], 1);
    }
    __syncthreads();

    // pass B: local top-K bin threshold (group sums + serial top-down scan)
    if (tid < 256) {
        int s = 0;
        #pragma unroll
        for (int b = 0; b < 16; ++b) s += hist[tid * 16 + b];
        s_grp[tid] = s;
    }
    __syncthreads();
    if (tid == 0) {
        int cum = 0, g = 255;
        for (; g > 0; --g) {
            if (cum + s_grp[g] >= K) break;
            cum += s_grp[g];
        }
        int tb = g * 16;
        for (int b = g * 16 + 15; ; --b) {
            cum += hist[b];
            if (cum >= K || b == g * 16) { tb = b; break; }
        }
        s_tbin = tb;
    }
    __syncthreads();
    const uint32_t tbin = (uint32_t)s_tbin;

    // pass C: re-read chunk (cache-hot at 1 block/CU), push candidates
    int* ctr = &counters[row];
    float* cVrow = candV + (size_t)row * cap;
    int*   cIrow = candI + (size_t)row * cap;
    for (int i = tid; i < N4C; i += TPB1) {
        float4 v = rowp[i];
        float s[4] = { v.x / T, v.y / T, v.z / T, v.w / T };
        int e = c0 + i * 4;
        #pragma unroll
        for (int c = 0; c < 4; ++c) {
            if ((f2ord(s[c]) >> 20) >= tbin) {
                int p = atomicAdd(ctr, 1);
                if (p < cap) { cVrow[p] = s[c]; cIrow[p] = e + c; }
            }
        }
    }

    // pass D: zero-fill probs chunk
    const float4 z4 = make_float4(0.0f, 0.0f, 0.0f, 0.0f);
    for (int i = tid; i < N4C; i += TPB1) orow[i] = z4;
}

// ---------------------------------------------------------------------------
// K2: per-row finalize (proven in round 4). Prune candidates via exact
// 4096-bin hist (kth bin), rank-sort survivors, verified serial top-k/top-p
// math with PARALLEL expf, Gumbel-argmax, scatter probs + token.
// ---------------------------------------------------------------------------
extern "C" __global__ __launch_bounds__(512)
void finalize_kernel(const float* __restrict__ topp_p,
                     const int*   __restrict__ topk_p,
                     const float* __restrict__ candV,
                     const int*   __restrict__ candI,
                     const int*   __restrict__ counters,
                     float* __restrict__ out,
                     int batch, int cap) {
    const int row  = blockIdx.x;
    const int tid  = threadIdx.x;
    const int nthr = blockDim.x;

    const float thresh = 1.0f - topp_p[0];
    const int   K      = topk_p[0];

    __shared__ float    cV[CAND_CAP];
    __shared__ int      cI[CAND_CAP];
    __shared__ uint32_t h2[BINS];
    __shared__ int      s_grp[256];
    __shared__ float    fV[FILT_CAP];
    __shared__ int      fI[FILT_CAP];
    __shared__ float    sV[FILT_CAP];
    __shared__ int      sI[FILT_CAP];
    __shared__ float    eArr[KEEP_CAP * 2];
    __shared__ float    s_gs[KEEP_CAP];
    __shared__ int      s_bstar, s_cnt2, s_Kp, s_M, s_token;
    __shared__ float    s_Z2;

    const int n = min(counters[row], cap);
    const float* cVrow = candV + (size_t)row * cap;
    const int*   cIrow = candI + (size_t)row * cap;
    for (int i = tid; i < n; i += nthr) { cV[i] = cVrow[i]; cI[i] = cIrow[i]; }
    for (int i = tid; i < BINS; i += nthr) h2[i] = 0u;
    if (tid == 0) s_cnt2 = 0;
    __syncthreads();

    // exact kth-value bin among candidates (superset of global top-K)
    for (int i = tid; i < n; i += nthr) atomicAdd(&h2[f2ord(cV[i]) >> 20], 1u);
    __syncthreads();
    if (tid < 256) {
        int s = 0;
        #pragma unroll
        for (int b = 0; b < 16; ++b) s += (int)h2[tid * 16 + b];
        s_grp[tid] = s;
    }
    __syncthreads();
    if (tid == 0) {
        int cum = 0, g = 255;
        for (; g > 0; --g) {
            if (cum + s_grp[g] >= K) break;
            cum += s_grp[g];
        }
        int tb = g * 16;
        for (int b = g * 16 + 15; ; --b) {
            cum += (int)h2[b];
            if (cum >= K || b == g * 16) { tb = b; break; }
        }
        s_bstar = tb;
    }
    __syncthreads();
    const uint32_t bstar = (uint32_t)s_bstar;

    // filter to bin >= bstar (keeps all >= kth value, incl. ties)
    for (int i = tid; i < n; i += nthr) {
        if ((f2ord(cV[i]) >> 20) >= bstar) {
            int p = atomicAdd(&s_cnt2, 1);
            if (p < FILT_CAP) { fV[p] = cV[i]; fI[p] = cI[i]; }
        }
    }
    __syncthreads();
    const int n2 = min(s_cnt2, FILT_CAP);

    // rank sort descending (unique total order via index tiebreak)
    for (int j = tid; j < n2; j += nthr) {
        float vj = fV[j]; int ij = fI[j];
        int r = 0;
        for (int l = 0; l < n2; ++l) {
            float vl = fV[l];
            r += (vl > vj) || (vl == vj && fI[l] < ij);
        }
        sV[r] = vj; sI[r] = ij;
    }
    __syncthreads();

    // Kp = top-k survivor count (ties at kth kept), then parallel expf
    if (tid == 0) {
        int Keff = min(K, n2);
        float kth = sV[Keff - 1];
        int Kp = Keff;
        while (Kp < n2 && sV[Kp] == kth) ++Kp;
        if (Kp > KEEP_CAP * 2) Kp = KEEP_CAP * 2;
        s_Kp = Kp;
    }
    __syncthreads();
    const int Kp = s_Kp;
    const float m = sV[0];
    for (int j = tid; j < Kp; j += nthr) eArr[j] = expf(sV[j] - m);
    __syncthreads();

    // serial part is adds/divides only (verified accumulation order)
    if (tid == 0) {
        float Z = 0.0f;
        for (int j = Kp - 1; j >= 0; --j) Z += eArr[j];
        float cum = 0.0f; int jcut = 0;
        for (int j = Kp - 1; j >= 0; --j) {
            cum += eArr[j] / Z;
            if (cum > thresh) { jcut = j; break; }
        }
        int M = jcut + 1;
        if (M > KEEP_CAP) M = KEEP_CAP;
        float Z2 = 0.0f;
        for (int j = 0; j < M; ++j) Z2 += eArr[j];
        s_M = M; s_Z2 = Z2;
    }
    __syncthreads();
    const int M = s_M;
    const float Z2 = s_Z2;

    if (tid < M) {
        uint64_t flat = (uint64_t)row * VOCAB + (uint32_t)sI[tid];
        s_gs[tid] = sV[tid] + gumbel_at(flat);
    }
    __syncthreads();
    if (tid == 0) {
        float bs = -__builtin_inff(); int bi = 0x7fffffff;
        for (int j = 0; j < M; ++j) {
            float s = s_gs[j]; int c = sI[j];
            if (s > bs || (s == bs && c < bi)) { bs = s; bi = c; }
        }
        s_token = bi;
    }
    __syncthreads();

    // probs row already zeroed by K1 — scatter kept probs + token
    for (int j = tid; j < M; j += nthr) {
        out[batch + (size_t)row * VOCAB + sI[j]] = eArr[j] / Z2;
    }
    if (tid == 0) out[row] = (float)s_token;
}

extern "C" void kernel_launch(void* const* d_in, const int* in_sizes, int n_in,
                              void* d_out, int out_size, void* d_ws, size_t ws_size,
                              hipStream_t stream) {
    (void)n_in; (void)out_size;
    const float* logits = (const float*)d_in[0];
    const float* temp   = (const float*)d_in[1];
    const float* topp   = (const float*)d_in[2];
    const int*   topk   = (const int*)d_in[3];
    float* out = (float*)d_out;

    const int batch = in_sizes[0] / VOCAB;

    // ws layout: [counters: batch ints][candV: batch*cap floats][candI: batch*cap ints]
    size_t ctr_bytes = ((size_t)batch * sizeof(int) + 255) & ~(size_t)255;
    int cap = CAND_CAP;
    if (ws_size > ctr_bytes) {
        size_t per_row = (ws_size - ctr_bytes) / ((size_t)batch * 8);
        if (per_row < (size_t)cap) cap = (int)per_row;
    }
    int*   counters = (int*)d_ws;
    float* candV    = (float*)((char*)d_ws + ctr_bytes);
    int*   candI    = (int*)(candV + (size_t)batch * cap);

    hipMemsetAsync(counters, 0, (size_t)batch * sizeof(int), stream);

    stage_kernel<<<batch * BPR, TPB1, 0, stream>>>(
        logits, temp, topk, out, candV, candI, counters, batch, cap);

    finalize_kernel<<<batch, 512, 0, stream>>>(
        topp, topk, candV, candI, counters, out, batch, cap);
}

// Round 6
// 108.102 us; speedup vs baseline: 5.1217x; 1.0051x over previous
//
#include <hip/hip_runtime.h>
#include <stdint.h>

#define VOCAB     128000
#define BINS      4096
#define BPR       2                 // blocks per row -> 256 blocks = 1 per CU
#define TPB1      1024              // threads per block (stage pass)
#define CHUNK     (VOCAB / BPR)     // 64000 floats per block
#define N4C       (CHUNK / 4)       // 16000 float4 per block
#define U1        8                 // pass-1 load unroll (MLP)
#define U2        4                 // pass-C load unroll
#define CAND_CAP  2048              // per-row candidate capacity
#define FILT_CAP  512               // post-prune capacity in finalize
#define KEEP_CAP  128

__device__ __forceinline__ uint32_t rotl32(uint32_t x, uint32_t r) {
    return (x << r) | (x >> (32u - r));
}

// monotone float -> uint transform (total order)
__device__ __forceinline__ uint32_t f2ord(float f) {
    uint32_t u = __float_as_uint(f);
    return (u & 0x80000000u) ? ~u : (u | 0x80000000u);
}

// Threefry-2x32, 20 rounds, key = (0, 42)  [jax.random.key(42)] — verified round 1
__device__ __forceinline__ void threefry_0_42(uint32_t x0, uint32_t x1,
                                              uint32_t& o0, uint32_t& o1) {
    const uint32_t k0 = 0u, k1 = 42u;
    const uint32_t k2 = 0x1BD11BDAu ^ k0 ^ k1;
#define TF_RND(R) { x0 += x1; x1 = rotl32(x1, (R)); x1 ^= x0; }
    x0 += k0; x1 += k1;
    TF_RND(13) TF_RND(15) TF_RND(26) TF_RND(6)
    x0 += k1; x1 += k2 + 1u;
    TF_RND(17) TF_RND(29) TF_RND(16) TF_RND(24)
    x0 += k2; x1 += k0 + 2u;
    TF_RND(13) TF_RND(15) TF_RND(26) TF_RND(6)
    x0 += k0; x1 += k1 + 3u;
    TF_RND(17) TF_RND(29) TF_RND(16) TF_RND(24)
    x0 += k1; x1 += k2 + 4u;
    TF_RND(13) TF_RND(15) TF_RND(26) TF_RND(6)
    x0 += k2; x1 += k0 + 5u;
#undef TF_RND
    o0 = x0; o1 = x1;
}

__device__ __forceinline__ float gumbel_at(uint64_t flat) {
    uint32_t o0, o1;
    threefry_0_42((uint32_t)(flat >> 32), (uint32_t)flat, o0, o1);
    uint32_t bits = o0 ^ o1;
    float f = __uint_as_float((bits >> 9) | 0x3F800000u) - 1.0f;
    float u = (f == 0.0f) ? 1.17549435e-38f : f;
    return -logf(-logf(u));
}

// ---------------------------------------------------------------------------
// K1: half-row per block (256 blocks = 1/CU).
// pass 1: 8-deep unrolled read (8 loads in flight/wave), histogram scores,
//         fused zero-fill of probs chunk.
// pass B: local top-K bin threshold.
// pass C: 4-deep unrolled re-read (L2/L3-hot), push candidates >= tbin.
// Union of per-chunk top-K supersets the global top-K.
// ---------------------------------------------------------------------------
extern "C" __global__ __launch_bounds__(TPB1)
void stage_kernel(const float* __restrict__ logits,
                  const float* __restrict__ temp_p,
                  const int*   __restrict__ topk_p,
                  float* __restrict__ out,
                  float* __restrict__ candV,
                  int*   __restrict__ candI,
                  int*   __restrict__ counters,
                  int batch, int cap) {
    const int row = blockIdx.x / BPR;
    const int sub = blockIdx.x % BPR;
    const int c0  = sub * CHUNK;
    const int tid = threadIdx.x;

    const float rT = 1.0f / temp_p[0];   // x*(1/T): validated in R4 (same absmax)
    const int   K  = topk_p[0];

    __shared__ int hist[BINS];
    __shared__ int s_grp[256];
    __shared__ int s_tbin;

    for (int i = tid; i < BINS; i += TPB1) hist[i] = 0;
    __syncthreads();

    const float4* rowp = (const float4*)(logits + (size_t)row * VOCAB) + (c0 >> 2);
    float4*       orow = (float4*)(out + batch + (size_t)row * VOCAB) + (c0 >> 2);
    const float4 z4 = make_float4(0.0f, 0.0f, 0.0f, 0.0f);

    // pass 1: 8 independent loads in flight, then consume; fused zero-fill
    for (int base = 0; base < N4C; base += TPB1 * U1) {
        float4 v[U1];
        int    idx[U1];
        #pragma unroll
        for (int u = 0; u < U1; ++u) {
            idx[u] = base + u * TPB1 + tid;
            if (idx[u] < N4C) v[u] = rowp[idx[u]];
        }
        #pragma unroll
        for (int u = 0; u < U1; ++u) {
            if (idx[u] < N4C) {
                atomicAdd(&hist[f2ord(v[u].x * rT) >> 20], 1);
                atomicAdd(&hist[f2ord(v[u].y * rT) >> 20], 1);
                atomicAdd(&hist[f2ord(v[u].z * rT) >> 20], 1);
                atomicAdd(&hist[f2ord(v[u].w * rT) >> 20], 1);
                orow[idx[u]] = z4;
            }
        }
    }
    __syncthreads();

    // pass B: local top-K bin threshold (group sums + serial top-down scan)
    if (tid < 256) {
        int s = 0;
        #pragma unroll
        for (int b = 0; b < 16; ++b) s += hist[tid * 16 + b];
        s_grp[tid] = s;
    }
    __syncthreads();
    if (tid == 0) {
        int cum = 0, g = 255;
        for (; g > 0; --g) {
            if (cum + s_grp[g] >= K) break;
            cum += s_grp[g];
        }
        int tb = g * 16;
        for (int b = g * 16 + 15; ; --b) {
            cum += hist[b];
            if (cum >= K || b == g * 16) { tb = b; break; }
        }
        s_tbin = tb;
    }
    __syncthreads();
    const uint32_t tbin = (uint32_t)s_tbin;

    // pass C: 4-deep unrolled re-read (cache-hot), push candidates
    int* ctr = &counters[row];
    float* cVrow = candV + (size_t)row * cap;
    int*   cIrow = candI + (size_t)row * cap;
    for (int base = 0; base < N4C; base += TPB1 * U2) {
        float4 v[U2];
        int    idx[U2];
        #pragma unroll
        for (int u = 0; u < U2; ++u) {
            idx[u] = base + u * TPB1 + tid;
            if (idx[u] < N4C) v[u] = rowp[idx[u]];
        }
        #pragma unroll
        for (int u = 0; u < U2; ++u) {
            if (idx[u] < N4C) {
                float ss[4] = { v[u].x * rT, v[u].y * rT, v[u].z * rT, v[u].w * rT };
                int e = c0 + idx[u] * 4;
                #pragma unroll
                for (int c = 0; c < 4; ++c) {
                    if ((f2ord(ss[c]) >> 20) >= tbin) {
                        int p = atomicAdd(ctr, 1);
                        if (p < cap) { cVrow[p] = ss[c]; cIrow[p] = e + c; }
                    }
                }
            }
        }
    }
}

// ---------------------------------------------------------------------------
// K2: per-row finalize (proven in round 4). Prune candidates via exact
// 4096-bin hist (kth bin), rank-sort survivors, verified serial top-k/top-p
// math with PARALLEL expf, Gumbel-argmax, scatter probs + token.
// ---------------------------------------------------------------------------
extern "C" __global__ __launch_bounds__(512)
void finalize_kernel(const float* __restrict__ topp_p,
                     const int*   __restrict__ topk_p,
                     const float* __restrict__ candV,
                     const int*   __restrict__ candI,
                     const int*   __restrict__ counters,
                     float* __restrict__ out,
                     int batch, int cap) {
    const int row  = blockIdx.x;
    const int tid  = threadIdx.x;
    const int nthr = blockDim.x;

    const float thresh = 1.0f - topp_p[0];
    const int   K      = topk_p[0];

    __shared__ float    cV[CAND_CAP];
    __shared__ int      cI[CAND_CAP];
    __shared__ uint32_t h2[BINS];
    __shared__ int      s_grp[256];
    __shared__ float    fV[FILT_CAP];
    __shared__ int      fI[FILT_CAP];
    __shared__ float    sV[FILT_CAP];
    __shared__ int      sI[FILT_CAP];
    __shared__ float    eArr[KEEP_CAP * 2];
    __shared__ float    s_gs[KEEP_CAP];
    __shared__ int      s_bstar, s_cnt2, s_Kp, s_M, s_token;
    __shared__ float    s_Z2;

    const int n = min(counters[row], cap);
    const float* cVrow = candV + (size_t)row * cap;
    const int*   cIrow = candI + (size_t)row * cap;
    for (int i = tid; i < n; i += nthr) { cV[i] = cVrow[i]; cI[i] = cIrow[i]; }
    for (int i = tid; i < BINS; i += nthr) h2[i] = 0u;
    if (tid == 0) s_cnt2 = 0;
    __syncthreads();

    // exact kth-value bin among candidates (superset of global top-K)
    for (int i = tid; i < n; i += nthr) atomicAdd(&h2[f2ord(cV[i]) >> 20], 1u);
    __syncthreads();
    if (tid < 256) {
        int s = 0;
        #pragma unroll
        for (int b = 0; b < 16; ++b) s += (int)h2[tid * 16 + b];
        s_grp[tid] = s;
    }
    __syncthreads();
    if (tid == 0) {
        int cum = 0, g = 255;
        for (; g > 0; --g) {
            if (cum + s_grp[g] >= K) break;
            cum += s_grp[g];
        }
        int tb = g * 16;
        for (int b = g * 16 + 15; ; --b) {
            cum += (int)h2[b];
            if (cum >= K || b == g * 16) { tb = b; break; }
        }
        s_bstar = tb;
    }
    __syncthreads();
    const uint32_t bstar = (uint32_t)s_bstar;

    // filter to bin >= bstar (keeps all >= kth value, incl. ties)
    for (int i = tid; i < n; i += nthr) {
        if ((f2ord(cV[i]) >> 20) >= bstar) {
            int p = atomicAdd(&s_cnt2, 1);
            if (p < FILT_CAP) { fV[p] = cV[i]; fI[p] = cI[i]; }
        }
    }
    __syncthreads();
    const int n2 = min(s_cnt2, FILT_CAP);

    // rank sort descending (unique total order via index tiebreak)
    for (int j = tid; j < n2; j += nthr) {
        float vj = fV[j]; int ij = fI[j];
        int r = 0;
        for (int l = 0; l < n2; ++l) {
            float vl = fV[l];
            r += (vl > vj) || (vl == vj && fI[l] < ij);
        }
        sV[r] = vj; sI[r] = ij;
    }
    __syncthreads();

    // Kp = top-k survivor count (ties at kth kept), then parallel expf
    if (tid == 0) {
        int Keff = min(K, n2);
        float kth = sV[Keff - 1];
        int Kp = Keff;
        while (Kp < n2 && sV[Kp] == kth) ++Kp;
        if (Kp > KEEP_CAP * 2) Kp = KEEP_CAP * 2;
        s_Kp = Kp;
    }
    __syncthreads();
    const int Kp = s_Kp;
    const float m = sV[0];
    for (int j = tid; j < Kp; j += nthr) eArr[j] = expf(sV[j] - m);
    __syncthreads();

    // serial part is adds/divides only (verified accumulation order)
    if (tid == 0) {
        float Z = 0.0f;
        for (int j = Kp - 1; j >= 0; --j) Z += eArr[j];
        float cum = 0.0f; int jcut = 0;
        for (int j = Kp - 1; j >= 0; --j) {
            cum += eArr[j] / Z;
            if (cum > thresh) { jcut = j; break; }
        }
        int M = jcut + 1;
        if (M > KEEP_CAP) M = KEEP_CAP;
        float Z2 = 0.0f;
        for (int j = 0; j < M; ++j) Z2 += eArr[j];
        s_M = M; s_Z2 = Z2;
    }
    __syncthreads();
    const int M = s_M;
    const float Z2 = s_Z2;

    if (tid < M) {
        uint64_t flat = (uint64_t)row * VOCAB + (uint32_t)sI[tid];
        s_gs[tid] = sV[tid] + gumbel_at(flat);
    }
    __syncthreads();
    if (tid == 0) {
        float bs = -__builtin_inff(); int bi = 0x7fffffff;
        for (int j = 0; j < M; ++j) {
            float s = s_gs[j]; int c = sI[j];
            if (s > bs || (s == bs && c < bi)) { bs = s; bi = c; }
        }
        s_token = bi;
    }
    __syncthreads();

    // probs row already zeroed by K1 — scatter kept probs + token
    for (int j = tid; j < M; j += nthr) {
        out[batch + (size_t)row * VOCAB + sI[j]] = eArr[j] / Z2;
    }
    if (tid == 0) out[row] = (float)s_token;
}

extern "C" void kernel_launch(void* const* d_in, const int* in_sizes, int n_in,
                              void* d_out, int out_size, void* d_ws, size_t ws_size,
                              hipStream_t stream) {
    (void)n_in; (void)out_size;
    const float* logits = (const float*)d_in[0];
    const float* temp   = (const float*)d_in[1];
    const float* topp   = (const float*)d_in[2];
    const int*   topk   = (const int*)d_in[3];
    float* out = (float*)d_out;

    const int batch = in_sizes[0] / VOCAB;

    // ws layout: [counters: batch ints][candV: batch*cap floats][candI: batch*cap ints]
    size_t ctr_bytes = ((size_t)batch * sizeof(int) + 255) & ~(size_t)255;
    int cap = CAND_CAP;
    if (ws_size > ctr_bytes) {
        size_t per_row = (ws_size - ctr_bytes) / ((size_t)batch * 8);
        if (per_row < (size_t)cap) cap = (int)per_row;
    }
    int*   counters = (int*)d_ws;
    float* candV    = (float*)((char*)d_ws + ctr_bytes);
    int*   candI    = (int*)(candV + (size_t)batch * cap);

    hipMemsetAsync(counters, 0, (size_t)batch * sizeof(int), stream);

    stage_kernel<<<batch * BPR, TPB1, 0, stream>>>(
        logits, temp, topk, out, candV, candI, counters, batch, cap);

    finalize_kernel<<<batch, 512, 0, stream>>>(
        topp, topk, candV, candI, counters, out, batch, cap);
}

// Round 7
// 55.107 us; speedup vs baseline: 10.0471x; 1.9617x over previous
//
#include <hip/hip_runtime.h>
#include <stdint.h>

#define VOCAB     128000
#define BINS      4096
#define BPR       2                 // blocks per row -> 256 blocks = 1 per CU
#define TPB1      1024              // threads per block (stage pass)
#define CHUNK     (VOCAB / BPR)     // 64000 floats per block
#define N4C       (CHUNK / 4)       // 16000 float4 per block
#define U1        8                 // pass-1 load unroll (MLP)
#define U2        4                 // pass-C load unroll
#define CAND_CAP  3072              // per-row candidate capacity (2 segments)
#define FILT_CAP  512               // post-prune capacity in finalize
#define KEEP_CAP  128

__device__ __forceinline__ uint32_t rotl32(uint32_t x, uint32_t r) {
    return (x << r) | (x >> (32u - r));
}

// monotone float -> uint transform (total order)
__device__ __forceinline__ uint32_t f2ord(float f) {
    uint32_t u = __float_as_uint(f);
    return (u & 0x80000000u) ? ~u : (u | 0x80000000u);
}

// Threefry-2x32, 20 rounds, key = (0, 42)  [jax.random.key(42)] — verified round 1
__device__ __forceinline__ void threefry_0_42(uint32_t x0, uint32_t x1,
                                              uint32_t& o0, uint32_t& o1) {
    const uint32_t k0 = 0u, k1 = 42u;
    const uint32_t k2 = 0x1BD11BDAu ^ k0 ^ k1;
#define TF_RND(R) { x0 += x1; x1 = rotl32(x1, (R)); x1 ^= x0; }
    x0 += k0; x1 += k1;
    TF_RND(13) TF_RND(15) TF_RND(26) TF_RND(6)
    x0 += k1; x1 += k2 + 1u;
    TF_RND(17) TF_RND(29) TF_RND(16) TF_RND(24)
    x0 += k2; x1 += k0 + 2u;
    TF_RND(13) TF_RND(15) TF_RND(26) TF_RND(6)
    x0 += k0; x1 += k1 + 3u;
    TF_RND(17) TF_RND(29) TF_RND(16) TF_RND(24)
    x0 += k1; x1 += k2 + 4u;
    TF_RND(13) TF_RND(15) TF_RND(26) TF_RND(6)
    x0 += k2; x1 += k0 + 5u;
#undef TF_RND
    o0 = x0; o1 = x1;
}

__device__ __forceinline__ float gumbel_at(uint64_t flat) {
    uint32_t o0, o1;
    threefry_0_42((uint32_t)(flat >> 32), (uint32_t)flat, o0, o1);
    uint32_t bits = o0 ^ o1;
    float f = __uint_as_float((bits >> 9) | 0x3F800000u) - 1.0f;
    float u = (f == 0.0f) ? 1.17549435e-38f : f;
    return -logf(-logf(u));
}

// ---------------------------------------------------------------------------
// K1: half-row per block (256 blocks = 1/CU).
// pass 1: 8-deep unrolled FULL read + fused zero-fill; SAMPLED histogram
//         (v.x of even-u float4s = 1/8 of scalars) -> 8x fewer DS atomics.
//         Sample-subset property keeps the top-K superset guarantee exact.
// pass B: local top-K bin threshold from the sampled hist.
// pass C: 4-deep unrolled re-read (cache-hot), push candidates >= tbin to
//         this block's PRIVATE segment; LDS counter; thread0 stores count.
// ---------------------------------------------------------------------------
extern "C" __global__ __launch_bounds__(TPB1)
void stage_kernel(const float* __restrict__ logits,
                  const float* __restrict__ temp_p,
                  const int*   __restrict__ topk_p,
                  float* __restrict__ out,
                  float* __restrict__ candV,
                  int*   __restrict__ candI,
                  int*   __restrict__ counters,
                  int batch, int cap) {
    const int row = blockIdx.x / BPR;
    const int sub = blockIdx.x % BPR;
    const int c0  = sub * CHUNK;
    const int tid = threadIdx.x;

    const float rT = 1.0f / temp_p[0];   // x*(1/T): validated in R4 (same absmax)
    const int   K  = topk_p[0];

    __shared__ int hist[BINS];
    __shared__ int s_grp[256];
    __shared__ int s_tbin;
    __shared__ int s_cnt;

    for (int i = tid; i < BINS; i += TPB1) hist[i] = 0;
    __syncthreads();

    const float4* rowp = (const float4*)(logits + (size_t)row * VOCAB) + (c0 >> 2);
    float4*       orow = (float4*)(out + batch + (size_t)row * VOCAB) + (c0 >> 2);
    const float4 z4 = make_float4(0.0f, 0.0f, 0.0f, 0.0f);

    // pass 1: full read (8 loads in flight) + zero-fill; hist on 1/8 sample
    for (int base = 0; base < N4C; base += TPB1 * U1) {
        float4 v[U1];
        int    idx[U1];
        #pragma unroll
        for (int u = 0; u < U1; ++u) {
            idx[u] = base + u * TPB1 + tid;
            if (idx[u] < N4C) v[u] = rowp[idx[u]];
        }
        #pragma unroll
        for (int u = 0; u < U1; ++u) {
            if (idx[u] < N4C) {
                if ((u & 1) == 0)
                    atomicAdd(&hist[f2ord(v[u].x * rT) >> 20], 1);
                orow[idx[u]] = z4;
            }
        }
    }
    __syncthreads();

    // pass B: sampled top-K bin threshold (group sums + serial top-down scan)
    if (tid < 256) {
        int s = 0;
        #pragma unroll
        for (int b = 0; b < 16; ++b) s += hist[tid * 16 + b];
        s_grp[tid] = s;
    }
    __syncthreads();
    if (tid == 0) {
        int cum = 0, g = 255;
        for (; g > 0; --g) {
            if (cum + s_grp[g] >= K) break;
            cum += s_grp[g];
        }
        int tb = g * 16;
        for (int b = g * 16 + 15; ; --b) {
            cum += hist[b];
            if (cum >= K || b == g * 16) { tb = b; break; }
        }
        s_tbin = tb;
        s_cnt  = 0;
    }
    __syncthreads();
    const uint32_t tbin = (uint32_t)s_tbin;

    // pass C: re-read chunk (cache-hot), push candidates to private segment
    const int cap2 = cap / 2;
    float* cVseg = candV + ((size_t)row * 2 + sub) * cap2;
    int*   cIseg = candI + ((size_t)row * 2 + sub) * cap2;
    for (int base = 0; base < N4C; base += TPB1 * U2) {
        float4 v[U2];
        int    idx[U2];
        #pragma unroll
        for (int u = 0; u < U2; ++u) {
            idx[u] = base + u * TPB1 + tid;
            if (idx[u] < N4C) v[u] = rowp[idx[u]];
        }
        #pragma unroll
        for (int u = 0; u < U2; ++u) {
            if (idx[u] < N4C) {
                float ss[4] = { v[u].x * rT, v[u].y * rT, v[u].z * rT, v[u].w * rT };
                int e = c0 + idx[u] * 4;
                #pragma unroll
                for (int c = 0; c < 4; ++c) {
                    if ((f2ord(ss[c]) >> 20) >= tbin) {
                        int p = atomicAdd(&s_cnt, 1);
                        if (p < cap2) { cVseg[p] = ss[c]; cIseg[p] = e + c; }
                    }
                }
            }
        }
    }
    __syncthreads();
    if (tid == 0) counters[row * 2 + sub] = min(s_cnt, cap2);
}

// ---------------------------------------------------------------------------
// K2: per-row finalize (proven). Load 2 segments, prune via exact 4096-bin
// hist (kth bin), rank-sort survivors, verified serial top-k/top-p math with
// PARALLEL expf, Gumbel-argmax, scatter probs + token.
// ---------------------------------------------------------------------------
extern "C" __global__ __launch_bounds__(512)
void finalize_kernel(const float* __restrict__ topp_p,
                     const int*   __restrict__ topk_p,
                     const float* __restrict__ candV,
                     const int*   __restrict__ candI,
                     const int*   __restrict__ counters,
                     float* __restrict__ out,
                     int batch, int cap) {
    const int row  = blockIdx.x;
    const int tid  = threadIdx.x;
    const int nthr = blockDim.x;

    const float thresh = 1.0f - topp_p[0];
    const int   K      = topk_p[0];

    __shared__ float    cV[CAND_CAP];
    __shared__ int      cI[CAND_CAP];
    __shared__ uint32_t h2[BINS];
    __shared__ int      s_grp[256];
    __shared__ float    fV[FILT_CAP];
    __shared__ int      fI[FILT_CAP];
    __shared__ float    sV[FILT_CAP];
    __shared__ int      sI[FILT_CAP];
    __shared__ float    eArr[KEEP_CAP * 2];
    __shared__ float    s_gs[KEEP_CAP];
    __shared__ int      s_bstar, s_cnt2, s_Kp, s_M, s_token;
    __shared__ float    s_Z2;

    const int cap2 = cap / 2;
    const int na = counters[row * 2];
    const int nb = counters[row * 2 + 1];
    const float* cVa = candV + ((size_t)row * 2) * cap2;
    const int*   cIa = candI + ((size_t)row * 2) * cap2;
    const float* cVb = candV + ((size_t)row * 2 + 1) * cap2;
    const int*   cIb = candI + ((size_t)row * 2 + 1) * cap2;
    for (int i = tid; i < na; i += nthr) { cV[i] = cVa[i]; cI[i] = cIa[i]; }
    for (int i = tid; i < nb; i += nthr) { cV[na + i] = cVb[i]; cI[na + i] = cIb[i]; }
    for (int i = tid; i < BINS; i += nthr) h2[i] = 0u;
    if (tid == 0) s_cnt2 = 0;
    __syncthreads();
    const int n = na + nb;

    // exact kth-value bin among candidates (superset of global top-K)
    for (int i = tid; i < n; i += nthr) atomicAdd(&h2[f2ord(cV[i]) >> 20], 1u);
    __syncthreads();
    if (tid < 256) {
        int s = 0;
        #pragma unroll
        for (int b = 0; b < 16; ++b) s += (int)h2[tid * 16 + b];
        s_grp[tid] = s;
    }
    __syncthreads();
    if (tid == 0) {
        int cum = 0, g = 255;
        for (; g > 0; --g) {
            if (cum + s_grp[g] >= K) break;
            cum += s_grp[g];
        }
        int tb = g * 16;
        for (int b = g * 16 + 15; ; --b) {
            cum += (int)h2[b];
            if (cum >= K || b == g * 16) { tb = b; break; }
        }
        s_bstar = tb;
    }
    __syncthreads();
    const uint32_t bstar = (uint32_t)s_bstar;

    // filter to bin >= bstar (keeps all >= kth value, incl. ties)
    for (int i = tid; i < n; i += nthr) {
        if ((f2ord(cV[i]) >> 20) >= bstar) {
            int p = atomicAdd(&s_cnt2, 1);
            if (p < FILT_CAP) { fV[p] = cV[i]; fI[p] = cI[i]; }
        }
    }
    __syncthreads();
    const int n2 = min(s_cnt2, FILT_CAP);

    // rank sort descending (unique total order via index tiebreak)
    for (int j = tid; j < n2; j += nthr) {
        float vj = fV[j]; int ij = fI[j];
        int r = 0;
        for (int l = 0; l < n2; ++l) {
            float vl = fV[l];
            r += (vl > vj) || (vl == vj && fI[l] < ij);
        }
        sV[r] = vj; sI[r] = ij;
    }
    __syncthreads();

    // Kp = top-k survivor count (ties at kth kept), then parallel expf
    if (tid == 0) {
        int Keff = min(K, n2);
        float kth = sV[Keff - 1];
        int Kp = Keff;
        while (Kp < n2 && sV[Kp] == kth) ++Kp;
        if (Kp > KEEP_CAP * 2) Kp = KEEP_CAP * 2;
        s_Kp = Kp;
    }
    __syncthreads();
    const int Kp = s_Kp;
    const float m = sV[0];
    for (int j = tid; j < Kp; j += nthr) eArr[j] = expf(sV[j] - m);
    __syncthreads();

    // serial part is adds/divides only (verified accumulation order)
    if (tid == 0) {
        float Z = 0.0f;
        for (int j = Kp - 1; j >= 0; --j) Z += eArr[j];
        float cum = 0.0f; int jcut = 0;
        for (int j = Kp - 1; j >= 0; --j) {
            cum += eArr[j] / Z;
            if (cum > thresh) { jcut = j; break; }
        }
        int M = jcut + 1;
        if (M > KEEP_CAP) M = KEEP_CAP;
        float Z2 = 0.0f;
        for (int j = 0; j < M; ++j) Z2 += eArr[j];
        s_M = M; s_Z2 = Z2;
    }
    __syncthreads();
    const int M = s_M;
    const float Z2 = s_Z2;

    if (tid < M) {
        uint64_t flat = (uint64_t)row * VOCAB + (uint32_t)sI[tid];
        s_gs[tid] = sV[tid] + gumbel_at(flat);
    }
    __syncthreads();
    if (tid == 0) {
        float bs = -__builtin_inff(); int bi = 0x7fffffff;
        for (int j = 0; j < M; ++j) {
            float s = s_gs[j]; int c = sI[j];
            if (s > bs || (s == bs && c < bi)) { bs = s; bi = c; }
        }
        s_token = bi;
    }
    __syncthreads();

    // probs row already zeroed by K1 — scatter kept probs + token
    for (int j = tid; j < M; j += nthr) {
        out[batch + (size_t)row * VOCAB + sI[j]] = eArr[j] / Z2;
    }
    if (tid == 0) out[row] = (float)s_token;
}

extern "C" void kernel_launch(void* const* d_in, const int* in_sizes, int n_in,
                              void* d_out, int out_size, void* d_ws, size_t ws_size,
                              hipStream_t stream) {
    (void)n_in; (void)out_size;
    const float* logits = (const float*)d_in[0];
    const float* temp   = (const float*)d_in[1];
    const float* topp   = (const float*)d_in[2];
    const int*   topk   = (const int*)d_in[3];
    float* out = (float*)d_out;

    const int batch = in_sizes[0] / VOCAB;

    // ws layout: [counters: batch*2 ints][candV: batch*cap floats][candI: batch*cap ints]
    size_t ctr_bytes = ((size_t)batch * BPR * sizeof(int) + 255) & ~(size_t)255;
    int cap = CAND_CAP;
    if (ws_size > ctr_bytes) {
        size_t per_row = (ws_size - ctr_bytes) / ((size_t)batch * 8);
        if (per_row < (size_t)cap) cap = (int)(per_row & ~(size_t)1);
    }
    int*   counters = (int*)d_ws;
    float* candV    = (float*)((char*)d_ws + ctr_bytes);
    int*   candI    = (int*)(candV + (size_t)batch * cap);

    stage_kernel<<<batch * BPR, TPB1, 0, stream>>>(
        logits, temp, topk, out, candV, candI, counters, batch, cap);

    finalize_kernel<<<batch, 512, 0, stream>>>(
        topp, topk, candV, candI, counters, out, batch, cap);
}

// Round 9
// 52.863 us; speedup vs baseline: 10.4736x; 1.0424x over previous
//
#include <hip/hip_runtime.h>
#include <stdint.h>

#define VOCAB     128000
#define BINS      4096
#define BPR       2                 // blocks per row -> 256 blocks = 1 per CU
#define TPB1      1024              // threads per block (stage pass)
#define CHUNK     (VOCAB / BPR)     // 64000 floats per block
#define N4C       (CHUNK / 4)       // 16000 float4 per block
#define NSAMP4    (N4C / 8)         // 2000 sampled float4 (every 8th 64B line)
#define U2        4                 // pass-C load unroll
#define CAND_CAP  3072              // per-row candidate capacity (2 segments)
#define FILT_CAP  512               // post-prune capacity in finalize
#define KEEP_CAP  128

typedef float nfloat4 __attribute__((ext_vector_type(4)));  // for nontemporal stores

__device__ __forceinline__ uint32_t rotl32(uint32_t x, uint32_t r) {
    return (x << r) | (x >> (32u - r));
}

// monotone float -> uint transform (total order)
__device__ __forceinline__ uint32_t f2ord(float f) {
    uint32_t u = __float_as_uint(f);
    return (u & 0x80000000u) ? ~u : (u | 0x80000000u);
}

// Threefry-2x32, 20 rounds, key = (0, 42)  [jax.random.key(42)] — verified round 1
__device__ __forceinline__ void threefry_0_42(uint32_t x0, uint32_t x1,
                                              uint32_t& o0, uint32_t& o1) {
    const uint32_t k0 = 0u, k1 = 42u;
    const uint32_t k2 = 0x1BD11BDAu ^ k0 ^ k1;
#define TF_RND(R) { x0 += x1; x1 = rotl32(x1, (R)); x1 ^= x0; }
    x0 += k0; x1 += k1;
    TF_RND(13) TF_RND(15) TF_RND(26) TF_RND(6)
    x0 += k1; x1 += k2 + 1u;
    TF_RND(17) TF_RND(29) TF_RND(16) TF_RND(24)
    x0 += k2; x1 += k0 + 2u;
    TF_RND(13) TF_RND(15) TF_RND(26) TF_RND(6)
    x0 += k0; x1 += k1 + 3u;
    TF_RND(17) TF_RND(29) TF_RND(16) TF_RND(24)
    x0 += k1; x1 += k2 + 4u;
    TF_RND(13) TF_RND(15) TF_RND(26) TF_RND(6)
    x0 += k2; x1 += k0 + 5u;
#undef TF_RND
    o0 = x0; o1 = x1;
}

__device__ __forceinline__ float gumbel_at(uint64_t flat) {
    uint32_t o0, o1;
    threefry_0_42((uint32_t)(flat >> 32), (uint32_t)flat, o0, o1);
    uint32_t bits = o0 ^ o1;
    float f = __uint_as_float((bits >> 9) | 0x3F800000u) - 1.0f;
    float u = (f == 0.0f) ? 1.17549435e-38f : f;
    return -logf(-logf(u));
}

// ---------------------------------------------------------------------------
// K1: half-row per block (256 blocks = 1/CU).
// pass 1: SAMPLED read — every 8th 64B line only (8 MB chip-wide), histogram
//         all 16 scalars of each sampled line (1/8 scalar fraction, same
//         atomic count as round 7). Any-subset threshold is conservative.
// pass B: local top-K bin threshold from the sampled hist.
// pass C: the ONLY full pass — read, filter+push candidates, and fused
//         NONTEMPORAL zero-fill store (don't evict L3-resident logits).
// ---------------------------------------------------------------------------
extern "C" __global__ __launch_bounds__(TPB1)
void stage_kernel(const float* __restrict__ logits,
                  const float* __restrict__ temp_p,
                  const int*   __restrict__ topk_p,
                  float* __restrict__ out,
                  float* __restrict__ candV,
                  int*   __restrict__ candI,
                  int*   __restrict__ counters,
                  int batch, int cap) {
    const int row = blockIdx.x / BPR;
    const int sub = blockIdx.x % BPR;
    const int c0  = sub * CHUNK;
    const int tid = threadIdx.x;

    const float rT = 1.0f / temp_p[0];   // x*(1/T): validated (same absmax)
    const int   K  = topk_p[0];

    __shared__ int hist[BINS];
    __shared__ int s_grp[256];
    __shared__ int s_tbin;
    __shared__ int s_cnt;

    for (int i = tid; i < BINS; i += TPB1) hist[i] = 0;
    __syncthreads();

    const float4* rowp = (const float4*)(logits + (size_t)row * VOCAB) + (c0 >> 2);
    float4*       orow = (float4*)(out + batch + (size_t)row * VOCAB) + (c0 >> 2);
    const nfloat4 z4 = { 0.0f, 0.0f, 0.0f, 0.0f };

    // pass 1: sampled-line read + histogram. s -> line group g = s>>2 (line
    // number g*8), float4-in-line c = s&3, float4 index = g*32 + c.
    for (int s = tid; s < NSAMP4; s += TPB1) {
        int i4 = ((s >> 2) << 5) + (s & 3);
        float4 v = rowp[i4];
        atomicAdd(&hist[f2ord(v.x * rT) >> 20], 1);
        atomicAdd(&hist[f2ord(v.y * rT) >> 20], 1);
        atomicAdd(&hist[f2ord(v.z * rT) >> 20], 1);
        atomicAdd(&hist[f2ord(v.w * rT) >> 20], 1);
    }
    __syncthreads();

    // pass B: sampled top-K bin threshold (group sums + serial top-down scan)
    if (tid < 256) {
        int s = 0;
        #pragma unroll
        for (int b = 0; b < 16; ++b) s += hist[tid * 16 + b];
        s_grp[tid] = s;
    }
    __syncthreads();
    if (tid == 0) {
        int cum = 0, g = 255;
        for (; g > 0; --g) {
            if (cum + s_grp[g] >= K) break;
            cum += s_grp[g];
        }
        int tb = g * 16;
        for (int b = g * 16 + 15; ; --b) {
            cum += hist[b];
            if (cum >= K || b == g * 16) { tb = b; break; }
        }
        s_tbin = tb;
        s_cnt  = 0;
    }
    __syncthreads();
    const uint32_t tbin = (uint32_t)s_tbin;

    // pass C: single full pass — read, filter+push, nontemporal zero-fill
    const int cap2 = cap / 2;
    float* cVseg = candV + ((size_t)row * 2 + sub) * cap2;
    int*   cIseg = candI + ((size_t)row * 2 + sub) * cap2;
    for (int base = 0; base < N4C; base += TPB1 * U2) {
        float4 v[U2];
        int    idx[U2];
        #pragma unroll
        for (int u = 0; u < U2; ++u) {
            idx[u] = base + u * TPB1 + tid;
            if (idx[u] < N4C) v[u] = rowp[idx[u]];
        }
        #pragma unroll
        for (int u = 0; u < U2; ++u) {
            if (idx[u] < N4C) {
                float ss[4] = { v[u].x * rT, v[u].y * rT, v[u].z * rT, v[u].w * rT };
                int e = c0 + idx[u] * 4;
                #pragma unroll
                for (int c = 0; c < 4; ++c) {
                    if ((f2ord(ss[c]) >> 20) >= tbin) {
                        int p = atomicAdd(&s_cnt, 1);
                        if (p < cap2) { cVseg[p] = ss[c]; cIseg[p] = e + c; }
                    }
                }
                __builtin_nontemporal_store(z4, (nfloat4*)&orow[idx[u]]);
            }
        }
    }
    __syncthreads();
    if (tid == 0) counters[row * 2 + sub] = min(s_cnt, cap2);
}

// ---------------------------------------------------------------------------
// K2: per-row finalize (proven). Load 2 segments, prune via exact 4096-bin
// hist (kth bin), rank-sort survivors, verified serial top-k/top-p math with
// PARALLEL expf, Gumbel-argmax, scatter probs + token.
// ---------------------------------------------------------------------------
extern "C" __global__ __launch_bounds__(512)
void finalize_kernel(const float* __restrict__ topp_p,
                     const int*   __restrict__ topk_p,
                     const float* __restrict__ candV,
                     const int*   __restrict__ candI,
                     const int*   __restrict__ counters,
                     float* __restrict__ out,
                     int batch, int cap) {
    const int row  = blockIdx.x;
    const int tid  = threadIdx.x;
    const int nthr = blockDim.x;

    const float thresh = 1.0f - topp_p[0];
    const int   K      = topk_p[0];

    __shared__ float    cV[CAND_CAP];
    __shared__ int      cI[CAND_CAP];
    __shared__ uint32_t h2[BINS];
    __shared__ int      s_grp[256];
    __shared__ float    fV[FILT_CAP];
    __shared__ int      fI[FILT_CAP];
    __shared__ float    sV[FILT_CAP];
    __shared__ int      sI[FILT_CAP];
    __shared__ float    eArr[KEEP_CAP * 2];
    __shared__ float    s_gs[KEEP_CAP];
    __shared__ int      s_bstar, s_cnt2, s_Kp, s_M, s_token;
    __shared__ float    s_Z2;

    const int cap2 = cap / 2;
    const int na = counters[row * 2];
    const int nb = counters[row * 2 + 1];
    const float* cVa = candV + ((size_t)row * 2) * cap2;
    const int*   cIa = candI + ((size_t)row * 2) * cap2;
    const float* cVb = candV + ((size_t)row * 2 + 1) * cap2;
    const int*   cIb = candI + ((size_t)row * 2 + 1) * cap2;
    for (int i = tid; i < na; i += nthr) { cV[i] = cVa[i]; cI[i] = cIa[i]; }
    for (int i = tid; i < nb; i += nthr) { cV[na + i] = cVb[i]; cI[na + i] = cIb[i]; }
    for (int i = tid; i < BINS; i += nthr) h2[i] = 0u;
    if (tid == 0) s_cnt2 = 0;
    __syncthreads();
    const int n = na + nb;

    // exact kth-value bin among candidates (superset of global top-K)
    for (int i = tid; i < n; i += nthr) atomicAdd(&h2[f2ord(cV[i]) >> 20], 1u);
    __syncthreads();
    if (tid < 256) {
        int s = 0;
        #pragma unroll
        for (int b = 0; b < 16; ++b) s += (int)h2[tid * 16 + b];
        s_grp[tid] = s;
    }
    __syncthreads();
    if (tid == 0) {
        int cum = 0, g = 255;
        for (; g > 0; --g) {
            if (cum + s_grp[g] >= K) break;
            cum += s_grp[g];
        }
        int tb = g * 16;
        for (int b = g * 16 + 15; ; --b) {
            cum += (int)h2[b];
            if (cum >= K || b == g * 16) { tb = b; break; }
        }
        s_bstar = tb;
    }
    __syncthreads();
    const uint32_t bstar = (uint32_t)s_bstar;

    // filter to bin >= bstar (keeps all >= kth value, incl. ties)
    for (int i = tid; i < n; i += nthr) {
        if ((f2ord(cV[i]) >> 20) >= bstar) {
            int p = atomicAdd(&s_cnt2, 1);
            if (p < FILT_CAP) { fV[p] = cV[i]; fI[p] = cI[i]; }
        }
    }
    __syncthreads();
    const int n2 = min(s_cnt2, FILT_CAP);

    // rank sort descending (unique total order via index tiebreak)
    for (int j = tid; j < n2; j += nthr) {
        float vj = fV[j]; int ij = fI[j];
        int r = 0;
        for (int l = 0; l < n2; ++l) {
            float vl = fV[l];
            r += (vl > vj) || (vl == vj && fI[l] < ij);
        }
        sV[r] = vj; sI[r] = ij;
    }
    __syncthreads();

    // Kp = top-k survivor count (ties at kth kept), then parallel expf
    if (tid == 0) {
        int Keff = min(K, n2);
        float kth = sV[Keff - 1];
        int Kp = Keff;
        while (Kp < n2 && sV[Kp] == kth) ++Kp;
        if (Kp > KEEP_CAP * 2) Kp = KEEP_CAP * 2;
        s_Kp = Kp;
    }
    __syncthreads();
    const int Kp = s_Kp;
    const float m = sV[0];
    for (int j = tid; j < Kp; j += nthr) eArr[j] = expf(sV[j] - m);
    __syncthreads();

    // serial part is adds/divides only (verified accumulation order)
    if (tid == 0) {
        float Z = 0.0f;
        for (int j = Kp - 1; j >= 0; --j) Z += eArr[j];
        float cum = 0.0f; int jcut = 0;
        for (int j = Kp - 1; j >= 0; --j) {
            cum += eArr[j] / Z;
            if (cum > thresh) { jcut = j; break; }
        }
        int M = jcut + 1;
        if (M > KEEP_CAP) M = KEEP_CAP;
        float Z2 = 0.0f;
        for (int j = 0; j < M; ++j) Z2 += eArr[j];
        s_M = M; s_Z2 = Z2;
    }
    __syncthreads();
    const int M = s_M;
    const float Z2 = s_Z2;

    if (tid < M) {
        uint64_t flat = (uint64_t)row * VOCAB + (uint32_t)sI[tid];
        s_gs[tid] = sV[tid] + gumbel_at(flat);
    }
    __syncthreads();
    if (tid == 0) {
        float bs = -__builtin_inff(); int bi = 0x7fffffff;
        for (int j = 0; j < M; ++j) {
            float s = s_gs[j]; int c = sI[j];
            if (s > bs || (s == bs && c < bi)) { bs = s; bi = c; }
        }
        s_token = bi;
    }
    __syncthreads();

    // probs row already zeroed by K1 — scatter kept probs + token
    for (int j = tid; j < M; j += nthr) {
        out[batch + (size_t)row * VOCAB + sI[j]] = eArr[j] / Z2;
    }
    if (tid == 0) out[row] = (float)s_token;
}

extern "C" void kernel_launch(void* const* d_in, const int* in_sizes, int n_in,
                              void* d_out, int out_size, void* d_ws, size_t ws_size,
                              hipStream_t stream) {
    (void)n_in; (void)out_size;
    const float* logits = (const float*)d_in[0];
    const float* temp   = (const float*)d_in[1];
    const float* topp   = (const float*)d_in[2];
    const int*   topk   = (const int*)d_in[3];
    float* out = (float*)d_out;

    const int batch = in_sizes[0] / VOCAB;

    // ws layout: [counters: batch*2 ints][candV: batch*cap floats][candI: batch*cap ints]
    size_t ctr_bytes = ((size_t)batch * BPR * sizeof(int) + 255) & ~(size_t)255;
    int cap = CAND_CAP;
    if (ws_size > ctr_bytes) {
        size_t per_row = (ws_size - ctr_bytes) / ((size_t)batch * 8);
        if (per_row < (size_t)cap) cap = (int)(per_row & ~(size_t)1);
    }
    int*   counters = (int*)d_ws;
    float* candV    = (float*)((char*)d_ws + ctr_bytes);
    int*   candI    = (int*)(candV + (size_t)batch * cap);

    stage_kernel<<<batch * BPR, TPB1, 0, stream>>>(
        logits, temp, topk, out, candV, candI, counters, batch, cap);

    finalize_kernel<<<batch, 512, 0, stream>>>(
        topp, topk, candV, candI, counters, out, batch, cap);
}